// Round 14
// baseline (342.375 us; speedup 1.0000x reference)
//
#include <hip/hip_runtime.h>
#include <hip/hip_bf16.h>
#include <math.h>

// Problem constants
#define B_ 256
#define S_ 24
#define N_ 207
#define U_ 64
#define A_ 256
#define H_ (N_*U_)          // 13248
#define H2_ (2*H_)          // 26496
#define BS_ (B_*S_)         // 6144
#define NF_ 129             // 1 + 2U
#define FP_ 192             // padded feature width of MB rows
#define KP_ 256             // padded node count (K of adj GEMMs)

typedef __attribute__((ext_vector_type(8))) short bf16x8;
typedef __attribute__((ext_vector_type(4))) float f32x4;

#define GAS __attribute__((address_space(1)))
#define LAS __attribute__((address_space(3)))

static __device__ __forceinline__ void gload16(const __hip_bfloat16* g, void* lds) {
    __builtin_amdgcn_global_load_lds((const GAS uint32_t*)g, (LAS uint32_t*)lds, 16, 0, 0);
}

// ---------------------------------------------------------------------------
// bf16 MFMA GEMM template (R8-R13-validated core). C = A[M,K] @ BT[N,K]^T.
// EPI: 1 = fp32 atomicAdd; 2 = bf16 store; 3 = bf16 remap (rh cols);
//      4 = sigmoid store; 5 = GRU epilogue + FUSED output projection.
// EPI=5 args: ep0=b_c, ep1=RU, ep2=hid, e_wt=weighted(B,H), e_pw=proj_W(129),
//             e_pb=proj_b, e_in=inputs(B,N), e_o0=out0(B,N). Requires BN=64.
// ---------------------------------------------------------------------------
template<int BM, int BN, int EPI>
__global__ __launch_bounds__(256)
void mfma_gemm(const __hip_bfloat16* __restrict__ A, int lda,
               const __hip_bfloat16* __restrict__ BT, int ldb,
               void* __restrict__ Cv, int ldc,
               int kchunk, int niter,
               const float* __restrict__ ep0,
               const float* __restrict__ ep1,
               const float* __restrict__ ep2,
               const float* __restrict__ e_wt,
               const float* __restrict__ e_pw,
               const float* __restrict__ e_pb,
               const float* __restrict__ e_in,
               float* __restrict__ e_o0)
{
    constexpr int FM = BM / 32, FN = BN / 32;
    __shared__ __align__(128) char smem[(BM + BN) * 128];
    char* As = smem;
    char* Bs = smem + BM * 128;

    const int tid  = threadIdx.x;
    const int lane = tid & 63;
    const int wid  = tid >> 6;
    const int wr   = wid >> 1, wc = wid & 1;

    const int n0 = blockIdx.x * BN;
    const int m0 = blockIdx.y * BM;
    const long k0 = (long)blockIdx.z * kchunk;

    const int qk = lane >> 4;
    const int fr = lane & 15;
    const int sw = (lane & 7) << 4;

    f32x4 acc[FM][FN] = {};

    for (int it = 0; it < niter; ++it) {
        const long kb = k0 + (long)it * 64;
        #pragma unroll
        for (int p = 0; p < BM / 32; ++p) {
            const int chunk = p * 4 + wid;
            const int blk   = chunk * 64 + lane;
            const int r     = blk >> 3;
            const int klog  = ((blk & 7) << 4) ^ ((r & 7) << 4);
            gload16(A + (size_t)(m0 + r) * lda + kb + (klog >> 1), As + chunk * 1024);
        }
        #pragma unroll
        for (int p = 0; p < BN / 32; ++p) {
            const int chunk = p * 4 + wid;
            const int blk   = chunk * 64 + lane;
            const int r     = blk >> 3;
            const int klog  = ((blk & 7) << 4) ^ ((r & 7) << 4);
            gload16(BT + (size_t)(n0 + r) * ldb + kb + (klog >> 1), Bs + chunk * 1024);
        }
        __syncthreads();
        #pragma unroll
        for (int ks = 0; ks < 2; ++ks) {
            const int ko = ks * 64 + qk * 16;
            bf16x8 a[FM], b[FN];
            #pragma unroll
            for (int i = 0; i < FM; ++i)
                a[i] = *(const bf16x8*)(As + (wr * (BM/2) + i * 16 + fr) * 128 + (ko ^ sw));
            #pragma unroll
            for (int j = 0; j < FN; ++j)
                b[j] = *(const bf16x8*)(Bs + (wc * (BN/2) + j * 16 + fr) * 128 + (ko ^ sw));
            #pragma unroll
            for (int i = 0; i < FM; ++i)
                #pragma unroll
                for (int j = 0; j < FN; ++j)
                    acc[i][j] = __builtin_amdgcn_mfma_f32_16x16x32_bf16(a[i], b[j], acc[i][j], 0, 0, 0);
        }
        __syncthreads();
    }

    // EPI=5 projection reduction buffer (aliases LDS, dead after last sync)
    float* rsum = (float*)smem;
    if (EPI == 5) {
        if (tid < BM) rsum[tid] = 0.f;
        __syncthreads();
    }
    float tpart[FM][4];
    if (EPI == 5) {
        #pragma unroll
        for (int mi = 0; mi < FM; ++mi)
            #pragma unroll
            for (int q = 0; q < 4; ++q) tpart[mi][q] = 0.f;
    }

    // C/D layout: col=lane&15, row=(lane>>4)*4+reg  [m89-verified]
    #pragma unroll
    for (int mi = 0; mi < FM; ++mi)
        #pragma unroll
        for (int ni = 0; ni < FN; ++ni) {
            const int rbase = m0 + wr * (BM/2) + mi * 16 + qk * 4;
            const int col   = n0 + wc * (BN/2) + ni * 16 + fr;
            #pragma unroll
            for (int q = 0; q < 4; ++q) {
                const int row = rbase + q;
                const float v = acc[mi][ni][q];
                if (EPI == 1) {
                    atomicAdd(&((float*)Cv)[(size_t)row * ldc + col], v);
                } else if (EPI == 2) {
                    ((__hip_bfloat16*)Cv)[(size_t)row * ldc + col] = __float2bfloat16(v);
                } else if (EPI == 3) {
                    const int bb = col >> 6, uu = col & 63;
                    ((__hip_bfloat16*)Cv)[((size_t)row * 256 + bb) * FP_ + 65 + uu] = __float2bfloat16(v);
                } else if (EPI == 4) {
                    float sv = v + ep0[col];
                    ((float*)Cv)[(size_t)row * ldc + col] = 1.f / (1.f + expf(-sv));
                } else { // EPI == 5
                    const int nn = row >> 8, bb = row & 255;
                    float cg = tanhf(v + ep0[col]);
                    float ug = ep1[(size_t)row * 128 + 64 + col];
                    const size_t hoff = (size_t)bb * H_ + nn * U_ + col;
                    float nh = ug * ep2[hoff] + (1.f - ug) * cg;
                    ((float*)Cv)[hoff] = nh;
                    tpart[mi][q] += nh * e_pw[col] + e_wt[hoff] * e_pw[64 + col];
                }
            }
        }

    if (EPI == 5) {
        #pragma unroll
        for (int mi = 0; mi < FM; ++mi)
            #pragma unroll
            for (int q = 0; q < 4; ++q) {
                float t = tpart[mi][q];
                #pragma unroll
                for (int off = 8; off; off >>= 1) t += __shfl_xor(t, off, 16);
                if (fr == 0) {
                    const int rloc = wr * (BM/2) + mi * 16 + qk * 4 + q;
                    atomicAdd(&rsum[rloc], t);
                }
            }
        __syncthreads();
        if (tid < BM) {
            const int row = m0 + tid;
            const int nn = row >> 8, bb = row & 255;
            e_o0[bb * N_ + nn] = rsum[tid] + e_in[bb * N_ + nn] * e_pw[128] + e_pb[0];
        }
    }
}

// ---------------------------------------------------------------------------
// Fused attention GEMM, BM=64 (R12-validated geometry), deep split-K z=23:
//   y in [0,96):   P  += enc_f32[y*64 ..] @ We^T   (BN=256)
//   y in [96,100): T1 += hid_f32[(y-96)*64 ..] @ Wh^T
// Grid (1,100,23) = 2300 blocks (~9/CU) — latency hidden by wave overlap
// (R13 lesson: BM=128 at 450 blocks was latency-bound, 8% MfmaUtil).
// ---------------------------------------------------------------------------
__global__ __launch_bounds__(256)
void gemm_enchid(const float* __restrict__ Aenc,
                 const float* __restrict__ Ahid,
                 const __hip_bfloat16* __restrict__ WTBF,
                 float* __restrict__ P, float* __restrict__ T1,
                 int kchunk, int niter)
{
    __shared__ __align__(128) char smem[(64 + 256) * 128];
    char* As = smem;            // 8 KB
    char* Bs = smem + 64*128;   // 32 KB

    const int tid  = threadIdx.x;
    const int lane = tid & 63;
    const int wid  = tid >> 6;
    const int wr   = wid >> 1, wc = wid & 1;

    const bool isH = (blockIdx.y >= 96);
    const float* A = isH ? Ahid : Aenc;
    const int m0   = (isH ? (blockIdx.y - 96) : blockIdx.y) * 64;
    const __hip_bfloat16* BT = WTBF + (isH ? 0 : H_);
    float* C = isH ? T1 : P;

    const long k0 = (long)blockIdx.z * kchunk;

    const int qk = lane >> 4;
    const int fr = lane & 15;
    const int sw = (lane & 7) << 4;

    f32x4 acc[2][8] = {};

    for (int it = 0; it < niter; ++it) {
        const long kb = k0 + (long)it * 64;
        // ---- A: fp32 -> bf16 reg-staged; 512 16B-chunks, 2/thread ----
        #pragma unroll
        for (int h = 0; h < 2; ++h) {
            const int c  = h * 256 + tid;      // chunk 0..511
            const int r  = c >> 3;             // tile row 0..63
            const int kc = c & 7;
            const float* src = A + (size_t)(m0 + r) * H_ + kb + kc * 8;
            const float4 x = *(const float4*)(src);
            const float4 y = *(const float4*)(src + 4);
            union { __hip_bfloat16 hh[8]; int4 u; } pk;
            pk.hh[0] = __float2bfloat16(x.x); pk.hh[1] = __float2bfloat16(x.y);
            pk.hh[2] = __float2bfloat16(x.z); pk.hh[3] = __float2bfloat16(x.w);
            pk.hh[4] = __float2bfloat16(y.x); pk.hh[5] = __float2bfloat16(y.y);
            pk.hh[6] = __float2bfloat16(y.z); pk.hh[7] = __float2bfloat16(y.w);
            *(int4*)(As + r * 128 + ((kc << 4) ^ ((r & 7) << 4))) = pk.u;
        }
        // ---- B: gload16 pre-swizzled ----
        #pragma unroll
        for (int p = 0; p < 8; ++p) {
            const int chunk = p * 4 + wid;
            const int blk   = chunk * 64 + lane;
            const int r     = blk >> 3;
            const int klog  = ((blk & 7) << 4) ^ ((r & 7) << 4);
            gload16(BT + (size_t)r * H2_ + kb + (klog >> 1), Bs + chunk * 1024);
        }
        __syncthreads();
        #pragma unroll
        for (int ks = 0; ks < 2; ++ks) {
            const int ko = ks * 64 + qk * 16;
            bf16x8 a[2], b[8];
            #pragma unroll
            for (int i = 0; i < 2; ++i)
                a[i] = *(const bf16x8*)(As + (wr * 32 + i * 16 + fr) * 128 + (ko ^ sw));
            #pragma unroll
            for (int j = 0; j < 8; ++j)
                b[j] = *(const bf16x8*)(Bs + (wc * 128 + j * 16 + fr) * 128 + (ko ^ sw));
            #pragma unroll
            for (int i = 0; i < 2; ++i)
                #pragma unroll
                for (int j = 0; j < 8; ++j)
                    acc[i][j] = __builtin_amdgcn_mfma_f32_16x16x32_bf16(a[i], b[j], acc[i][j], 0, 0, 0);
        }
        __syncthreads();
    }

    #pragma unroll
    for (int mi = 0; mi < 2; ++mi)
        #pragma unroll
        for (int ni = 0; ni < 8; ++ni) {
            const int rbase = m0 + wr * 32 + mi * 16 + qk * 4;
            const int col   = wc * 128 + ni * 16 + fr;
            #pragma unroll
            for (int q = 0; q < 4; ++q)
                atomicAdd(&C[(size_t)(rbase + q) * A_ + col], acc[mi][ni][q]);
        }
}

// fused prep: y<8 -> attn_W transpose tiles; y==8 -> T1 init + P zero
__global__ __launch_bounds__(256)
void prep_kernel(const float* __restrict__ attnW, __hip_bfloat16* __restrict__ WTBF,
                 const float* __restrict__ ab, float* __restrict__ T1,
                 float4* __restrict__ P4) {
    const int tid = threadIdx.x;
    if (blockIdx.y == 8) {
        for (int i = blockIdx.x * 256 + tid; i < 458752; i += 828 * 256) {
            if (i < 65536) T1[i] = ab[i & 255];
            else           P4[i - 65536] = make_float4(0.f, 0.f, 0.f, 0.f);
        }
        return;
    }
    __shared__ float tile[32][33];
    const int h0 = blockIdx.x * 32, a0 = blockIdx.y * 32;
    const int tx = tid & 31, ty4 = tid >> 5;
    #pragma unroll
    for (int i = 0; i < 4; ++i) {
        int r = ty4 * 4 + i;
        tile[r][tx] = attnW[(size_t)(h0 + r) * A_ + a0 + tx];
    }
    __syncthreads();
    #pragma unroll
    for (int i = 0; i < 4; ++i) {
        int r = ty4 * 4 + i;
        WTBF[(size_t)(a0 + r) * H2_ + h0 + tx] = __float2bfloat16(tile[tx][r]);
    }
}

// scores[q] = sum_a tanh(P[q,a] + T1[b,a]) * v[a],  q = s*256+b
__global__ __launch_bounds__(256)
void scores_kernel(const float* __restrict__ P, const float* __restrict__ T1,
                   const float* __restrict__ v, float* __restrict__ SC) {
    int wave = threadIdx.x >> 6, lane = threadIdx.x & 63;
    int q = blockIdx.x * 4 + wave;
    if (q >= BS_) return;
    int b = q & 255;
    float s = 0.f;
    #pragma unroll
    for (int a = lane; a < A_; a += 64) {
        float e = tanhf(P[(size_t)q * A_ + a] + T1[b * A_ + a]);
        s += e * v[a];
    }
    #pragma unroll
    for (int off = 32; off; off >>= 1) s += __shfl_down(s, off, 64);
    if (lane == 0) SC[q] = s;
}

// weighted[b,h] = softmax_s(SC[:,b]) . enc_f32[:,b,h]
__global__ __launch_bounds__(256)
void weighted_f32_kernel(const float4* __restrict__ E4, const float* __restrict__ SC,
                         float4* __restrict__ WT4) {
    int g = blockIdx.x * 256 + threadIdx.x;            // B_*H_/4
    int b = g / (H_ / 4), c = g % (H_ / 4);
    float sc[S_];
    float mx = -1e30f;
    #pragma unroll
    for (int s = 0; s < S_; ++s) { sc[s] = SC[s * B_ + b]; mx = fmaxf(mx, sc[s]); }
    float sum = 0.f;
    #pragma unroll
    for (int s = 0; s < S_; ++s) { sc[s] = expf(sc[s] - mx); sum += sc[s]; }
    float inv = 1.f / sum;
    float4 acc = make_float4(0.f, 0.f, 0.f, 0.f);
    #pragma unroll
    for (int s = 0; s < S_; ++s) {
        float w = sc[s] * inv;
        float4 ev = E4[(size_t)(s * B_ + b) * (H_ / 4) + c];
        acc.x += w * ev.x; acc.y += w * ev.y;
        acc.z += w * ev.z; acc.w += w * ev.w;
    }
    WT4[(size_t)b * (H_ / 4) + c] = acc;
}

// CAT_T builder (y<4) + phase-B weight prep (y==4, grid-stride).
__global__ __launch_bounds__(256)
void catT_prepB_kernel(const float* __restrict__ inp, const float* __restrict__ WT,
                       const float* __restrict__ hid, __hip_bfloat16* __restrict__ CT,
                       const float* __restrict__ adj, const float* __restrict__ Wru,
                       const float* __restrict__ Wc, __hip_bfloat16* __restrict__ ADJ,
                       __hip_bfloat16* __restrict__ WRUT, __hip_bfloat16* __restrict__ WCT) {
    const int tid = threadIdx.x;
    if (blockIdx.y == 4) {
        for (int i = blockIdx.x * 256 + tid; i < 102400; i += 65536) {
            if (i < 65536) {
                int r = i >> 8, c = i & 255;
                ADJ[i] = __float2bfloat16((r < N_ && c < N_) ? adj[r * N_ + c] : 0.f);
            } else if (i < 90112) {
                int idx = i - 65536;
                int j = idx / FP_, f = idx % FP_;
                WRUT[idx] = __float2bfloat16(f < NF_ ? Wru[f * 128 + j] : 0.f);
            } else {
                int idx = i - 90112;
                int j = idx / FP_, f = idx % FP_;
                WCT[idx] = __float2bfloat16(f < NF_ ? Wc[f * 64 + j] : 0.f);
            }
        }
        return;
    }
    __shared__ float ww[64][65];
    __shared__ float wh[64][65];
    __shared__ float wi[64];
    const int b = blockIdx.x;
    const int k0 = blockIdx.y * 64;
    #pragma unroll
    for (int i = 0; i < 16; ++i) {
        int idx = tid + i * 256;
        int kn = idx >> 6, f = idx & 63;
        int k = k0 + kn;
        bool vld = (k < N_);
        ww[kn][f] = vld ? WT [(size_t)b * H_ + k * 64 + f] : 0.f;
        wh[kn][f] = vld ? hid[(size_t)b * H_ + k * 64 + f] : 0.f;
    }
    if (tid < 64) wi[tid] = (k0 + tid < N_) ? inp[b * N_ + k0 + tid] : 0.f;
    __syncthreads();
    #pragma unroll
    for (int i = 0; i < 6; ++i) {
        int cid = tid + i * 256;
        int f = cid >> 3, kk = (cid & 7) * 8;
        union { __hip_bfloat16 h[8]; bf16x8 v; } pk;
        #pragma unroll
        for (int j = 0; j < 8; ++j) {
            float x;
            if (f == 0)        x = wi[kk + j];
            else if (f <= 64)  x = ww[kk + j][f - 1];
            else if (f <= 128) x = wh[kk + j][f - 65];
            else               x = 0.f;
            pk.h[j] = __float2bfloat16(x);
        }
        *(bf16x8*)(CT + ((size_t)b * FP_ + f) * KP_ + k0 + kk) = pk.v;
    }
}

// RH_T builder: rows (b*64+u), cols k: r[k,b,u]*h[b,k,u], bf16
__global__ __launch_bounds__(256)
void rhT_kernel(const float* __restrict__ RU, const float* __restrict__ hid,
                __hip_bfloat16* __restrict__ RT) {
    __shared__ float rh[64][65];
    const int b = blockIdx.x, k0 = blockIdx.y * 64, tid = threadIdx.x;
    #pragma unroll
    for (int i = 0; i < 16; ++i) {
        int idx = tid + i * 256;
        int kn = idx >> 6, u = idx & 63;
        int k = k0 + kn;
        float v = 0.f;
        if (k < N_)
            v = RU[((size_t)k * 256 + b) * 128 + u] * hid[(size_t)b * H_ + k * 64 + u];
        rh[kn][u] = v;
    }
    __syncthreads();
    #pragma unroll
    for (int i = 0; i < 2; ++i) {
        int cid = tid + i * 256;
        int u = cid >> 3, kk = (cid & 7) * 8;
        union { __hip_bfloat16 h[8]; bf16x8 v; } pk;
        #pragma unroll
        for (int j = 0; j < 8; ++j) pk.h[j] = __float2bfloat16(rh[kk + j][u]);
        *(bf16x8*)(RT + ((size_t)b * 64 + u) * KP_ + k0 + kk) = pk.v;
    }
}

extern "C" void kernel_launch(void* const* d_in, const int* in_sizes, int n_in,
                              void* d_out, int out_size, void* d_ws, size_t ws_size,
                              hipStream_t stream) {
    const float* inp    = (const float*)d_in[0];
    const float* enc    = (const float*)d_in[1];
    const float* hid    = (const float*)d_in[2];
    const float* adj    = (const float*)d_in[3];
    const float* attn_W = (const float*)d_in[4];
    const float* attn_b = (const float*)d_in[5];
    const float* attn_v = (const float*)d_in[6];
    const float* W_ru   = (const float*)d_in[7];
    const float* b_ru   = (const float*)d_in[8];
    const float* W_c    = (const float*)d_in[9];
    const float* b_c    = (const float*)d_in[10];
    const float* proj_W = (const float*)d_in[11];
    const float* proj_b = (const float*)d_in[12];

    float* out0 = (float*)d_out;
    float* out2 = out0 + (size_t)B_ * N_;

    // Workspace (float offsets) — R8-validated region map kept.
    float* ws  = (float*)d_ws;
    float* T1  = ws;                      // 65536
    float* P   = T1 + 65536;              // 1572864
    float* SC  = P  + 1572864;            // 6144
    float* AW  = SC + 6144;               // 6144 (layout kept stable)
    float* WT  = AW + 6144;               // 3391488
    float* BIG = WT + 3391488;            // off 5042176
    __hip_bfloat16* WT_BF  = (__hip_bfloat16*)(BIG + 40697856);
    __hip_bfloat16* CAT_T  = (__hip_bfloat16*)BIG;
    __hip_bfloat16* MB_BF  = (__hip_bfloat16*)(BIG + 6291456);
    __hip_bfloat16* RH_T   = (__hip_bfloat16*)(BIG + 12582912);
    float*          RU     = BIG + 14680064;
    __hip_bfloat16* ADJ_BF = (__hip_bfloat16*)(BIG + 21463040);
    __hip_bfloat16* WRUT   = (__hip_bfloat16*)(BIG + 21495808);
    __hip_bfloat16* WCT    = (__hip_bfloat16*)(BIG + 21508096);

    // --- prep: attn_W transpose (y<8) + T1/P init (y==8), one dispatch ---
    prep_kernel<<<dim3(H2_/32, 9), 256, 0, stream>>>(
        attn_W, WT_BF, attn_b, T1, (float4*)P);

    // --- attention: BM=64, deep split-K z=23 -> 2300 blocks (~9/CU) ---
    gemm_enchid<<<dim3(1, 100, 23), 256, 0, stream>>>(
        enc, hid, WT_BF, P, T1, 576, 9);

    scores_kernel<<<BS_/4, 256, 0, stream>>>(P, T1, attn_v, SC);
    weighted_f32_kernel<<<(B_*(H_/4))/256, 256, 0, stream>>>(
        (const float4*)enc, SC, (float4*)WT);

    // --- phase B ---
    catT_prepB_kernel<<<dim3(256, 5), 256, 0, stream>>>(
        inp, WT, hid, CAT_T, adj, W_ru, W_c, ADJ_BF, WRUT, WCT);

    mfma_gemm<64,64,2><<<dim3(768,4,1), 256, 0, stream>>>(
        ADJ_BF, KP_, CAT_T, KP_, MB_BF, 49152, 0, 4,
        nullptr, nullptr, nullptr, nullptr, nullptr, nullptr, nullptr, nullptr);

    mfma_gemm<64,64,4><<<dim3(2,828,1), 256, 0, stream>>>(
        MB_BF, FP_, WRUT, FP_, RU, 128, 0, 3,
        b_ru, nullptr, nullptr, nullptr, nullptr, nullptr, nullptr, nullptr);

    rhT_kernel<<<dim3(256,4), 256, 0, stream>>>(RU, hid, RH_T);

    mfma_gemm<64,64,3><<<dim3(256,4,1), 256, 0, stream>>>(
        ADJ_BF, KP_, RH_T, KP_, MB_BF, 0, 0, 4,
        nullptr, nullptr, nullptr, nullptr, nullptr, nullptr, nullptr, nullptr);

    // c-GEMM + GRU + FUSED projection -> out2 (newh) and out0
    mfma_gemm<64,64,5><<<dim3(1,828,1), 256, 0, stream>>>(
        MB_BF, FP_, WCT, FP_, out2, 0, 0, 3,
        b_c, RU, hid, WT, proj_W, proj_b, inp, out0);
}

// Round 15
// 282.785 us; speedup vs baseline: 1.2107x; 1.2107x over previous
//
#include <hip/hip_runtime.h>
#include <hip/hip_bf16.h>
#include <math.h>

// Problem constants
#define B_ 256
#define S_ 24
#define N_ 207
#define U_ 64
#define A_ 256
#define H_ (N_*U_)          // 13248
#define H2_ (2*H_)          // 26496
#define BS_ (B_*S_)         // 6144
#define NF_ 129             // 1 + 2U
#define FP_ 192             // padded feature width of MB rows
#define KP_ 256             // padded node count (K of adj GEMMs)
#define MR_ 6400            // unified attention rows: 6144 enc + 256 hid
#define ZSPL_ 9             // split-K partials

typedef __attribute__((ext_vector_type(8))) short bf16x8;
typedef __attribute__((ext_vector_type(4))) float f32x4;

#define GAS __attribute__((address_space(1)))
#define LAS __attribute__((address_space(3)))

static __device__ __forceinline__ void gload16(const __hip_bfloat16* g, void* lds) {
    __builtin_amdgcn_global_load_lds((const GAS uint32_t*)g, (LAS uint32_t*)lds, 16, 0, 0);
}

// ---------------------------------------------------------------------------
// bf16 MFMA GEMM template (R8-R14-validated core). C = A[M,K] @ BT[N,K]^T.
// EPI: 2 = bf16 store; 3 = bf16 remap (rh cols); 4 = sigmoid store;
//      5 = GRU epilogue + FUSED output projection (BN=64 required).
// ---------------------------------------------------------------------------
template<int BM, int BN, int EPI>
__global__ __launch_bounds__(256)
void mfma_gemm(const __hip_bfloat16* __restrict__ A, int lda,
               const __hip_bfloat16* __restrict__ BT, int ldb,
               void* __restrict__ Cv, int ldc,
               int kchunk, int niter,
               const float* __restrict__ ep0,
               const float* __restrict__ ep1,
               const float* __restrict__ ep2,
               const float* __restrict__ e_wt,
               const float* __restrict__ e_pw,
               const float* __restrict__ e_pb,
               const float* __restrict__ e_in,
               float* __restrict__ e_o0)
{
    constexpr int FM = BM / 32, FN = BN / 32;
    __shared__ __align__(128) char smem[(BM + BN) * 128];
    char* As = smem;
    char* Bs = smem + BM * 128;

    const int tid  = threadIdx.x;
    const int lane = tid & 63;
    const int wid  = tid >> 6;
    const int wr   = wid >> 1, wc = wid & 1;

    const int n0 = blockIdx.x * BN;
    const int m0 = blockIdx.y * BM;
    const long k0 = (long)blockIdx.z * kchunk;

    const int qk = lane >> 4;
    const int fr = lane & 15;
    const int sw = (lane & 7) << 4;

    f32x4 acc[FM][FN] = {};

    for (int it = 0; it < niter; ++it) {
        const long kb = k0 + (long)it * 64;
        #pragma unroll
        for (int p = 0; p < BM / 32; ++p) {
            const int chunk = p * 4 + wid;
            const int blk   = chunk * 64 + lane;
            const int r     = blk >> 3;
            const int klog  = ((blk & 7) << 4) ^ ((r & 7) << 4);
            gload16(A + (size_t)(m0 + r) * lda + kb + (klog >> 1), As + chunk * 1024);
        }
        #pragma unroll
        for (int p = 0; p < BN / 32; ++p) {
            const int chunk = p * 4 + wid;
            const int blk   = chunk * 64 + lane;
            const int r     = blk >> 3;
            const int klog  = ((blk & 7) << 4) ^ ((r & 7) << 4);
            gload16(BT + (size_t)(n0 + r) * ldb + kb + (klog >> 1), Bs + chunk * 1024);
        }
        __syncthreads();
        #pragma unroll
        for (int ks = 0; ks < 2; ++ks) {
            const int ko = ks * 64 + qk * 16;
            bf16x8 a[FM], b[FN];
            #pragma unroll
            for (int i = 0; i < FM; ++i)
                a[i] = *(const bf16x8*)(As + (wr * (BM/2) + i * 16 + fr) * 128 + (ko ^ sw));
            #pragma unroll
            for (int j = 0; j < FN; ++j)
                b[j] = *(const bf16x8*)(Bs + (wc * (BN/2) + j * 16 + fr) * 128 + (ko ^ sw));
            #pragma unroll
            for (int i = 0; i < FM; ++i)
                #pragma unroll
                for (int j = 0; j < FN; ++j)
                    acc[i][j] = __builtin_amdgcn_mfma_f32_16x16x32_bf16(a[i], b[j], acc[i][j], 0, 0, 0);
        }
        __syncthreads();
    }

    // EPI=5 projection reduction buffer (aliases LDS, dead after last sync)
    float* rsum = (float*)smem;
    if (EPI == 5) {
        if (tid < BM) rsum[tid] = 0.f;
        __syncthreads();
    }
    float tpart[FM][4];
    if (EPI == 5) {
        #pragma unroll
        for (int mi = 0; mi < FM; ++mi)
            #pragma unroll
            for (int q = 0; q < 4; ++q) tpart[mi][q] = 0.f;
    }

    // C/D layout: col=lane&15, row=(lane>>4)*4+reg  [m89-verified]
    #pragma unroll
    for (int mi = 0; mi < FM; ++mi)
        #pragma unroll
        for (int ni = 0; ni < FN; ++ni) {
            const int rbase = m0 + wr * (BM/2) + mi * 16 + qk * 4;
            const int col   = n0 + wc * (BN/2) + ni * 16 + fr;
            #pragma unroll
            for (int q = 0; q < 4; ++q) {
                const int row = rbase + q;
                const float v = acc[mi][ni][q];
                if (EPI == 2) {
                    ((__hip_bfloat16*)Cv)[(size_t)row * ldc + col] = __float2bfloat16(v);
                } else if (EPI == 3) {
                    const int bb = col >> 6, uu = col & 63;
                    ((__hip_bfloat16*)Cv)[((size_t)row * 256 + bb) * FP_ + 65 + uu] = __float2bfloat16(v);
                } else if (EPI == 4) {
                    float sv = v + ep0[col];
                    ((float*)Cv)[(size_t)row * ldc + col] = 1.f / (1.f + expf(-sv));
                } else { // EPI == 5
                    const int nn = row >> 8, bb = row & 255;
                    float cg = tanhf(v + ep0[col]);
                    float ug = ep1[(size_t)row * 128 + 64 + col];
                    const size_t hoff = (size_t)bb * H_ + nn * U_ + col;
                    float nh = ug * ep2[hoff] + (1.f - ug) * cg;
                    ((float*)Cv)[hoff] = nh;
                    tpart[mi][q] += nh * e_pw[col] + e_wt[hoff] * e_pw[64 + col];
                }
            }
        }

    if (EPI == 5) {
        #pragma unroll
        for (int mi = 0; mi < FM; ++mi)
            #pragma unroll
            for (int q = 0; q < 4; ++q) {
                float t = tpart[mi][q];
                #pragma unroll
                for (int off = 8; off; off >>= 1) t += __shfl_xor(t, off, 16);
                if (fr == 0) {
                    const int rloc = wr * (BM/2) + mi * 16 + qk * 4 + q;
                    atomicAdd(&rsum[rloc], t);   // LDS atomic — cheap
                }
            }
        __syncthreads();
        if (tid < BM) {
            const int row = m0 + tid;
            const int nn = row >> 8, bb = row & 255;
            e_o0[bb * N_ + nn] = rsum[tid] + e_in[bb * N_ + nn] * e_pw[128] + e_pb[0];
        }
    }
}

// ---------------------------------------------------------------------------
// Fused attention GEMM, BM=64/BN=256, split-K z=9, NO GLOBAL ATOMICS:
// each z stores its partial to Pz[z][grow][col] (plain coalesced stores).
// Rows: grow 0..6143 = enc @ We^T; grow 6144..6399 = hid @ Wh^T.
// (R14 lesson: device-scope fp32 atomicAdd = memory-side RMW, ~1.5ns each;
//  14-38M of them dominated the kernel at 8% MfmaUtil.)
// ---------------------------------------------------------------------------
__global__ __launch_bounds__(256)
void gemm_enchid(const float* __restrict__ Aenc,
                 const float* __restrict__ Ahid,
                 const __hip_bfloat16* __restrict__ WTBF,
                 float* __restrict__ Pz,
                 int kchunk, int niter)
{
    __shared__ __align__(128) char smem[(64 + 256) * 128];
    char* As = smem;            // 8 KB
    char* Bs = smem + 64*128;   // 32 KB

    const int tid  = threadIdx.x;
    const int lane = tid & 63;
    const int wid  = tid >> 6;
    const int wr   = wid >> 1, wc = wid & 1;

    const bool isH = (blockIdx.y >= 96);
    const float* A = isH ? Ahid : Aenc;
    const int lm0  = (isH ? (blockIdx.y - 96) : blockIdx.y) * 64;  // local rows
    const int gm0  = (isH ? 6144 : 0) + lm0;                       // unified rows
    const __hip_bfloat16* BT = WTBF + (isH ? 0 : H_);

    const long k0 = (long)blockIdx.z * kchunk;

    const int qk = lane >> 4;
    const int fr = lane & 15;
    const int sw = (lane & 7) << 4;

    f32x4 acc[2][8] = {};

    for (int it = 0; it < niter; ++it) {
        const long kb = k0 + (long)it * 64;
        // ---- A: fp32 -> bf16 reg-staged; 512 16B-chunks, 2/thread ----
        #pragma unroll
        for (int h = 0; h < 2; ++h) {
            const int c  = h * 256 + tid;
            const int r  = c >> 3;
            const int kc = c & 7;
            const float* src = A + (size_t)(lm0 + r) * H_ + kb + kc * 8;
            const float4 x = *(const float4*)(src);
            const float4 y = *(const float4*)(src + 4);
            union { __hip_bfloat16 hh[8]; int4 u; } pk;
            pk.hh[0] = __float2bfloat16(x.x); pk.hh[1] = __float2bfloat16(x.y);
            pk.hh[2] = __float2bfloat16(x.z); pk.hh[3] = __float2bfloat16(x.w);
            pk.hh[4] = __float2bfloat16(y.x); pk.hh[5] = __float2bfloat16(y.y);
            pk.hh[6] = __float2bfloat16(y.z); pk.hh[7] = __float2bfloat16(y.w);
            *(int4*)(As + r * 128 + ((kc << 4) ^ ((r & 7) << 4))) = pk.u;
        }
        // ---- B: gload16 pre-swizzled ----
        #pragma unroll
        for (int p = 0; p < 8; ++p) {
            const int chunk = p * 4 + wid;
            const int blk   = chunk * 64 + lane;
            const int r     = blk >> 3;
            const int klog  = ((blk & 7) << 4) ^ ((r & 7) << 4);
            gload16(BT + (size_t)r * H2_ + kb + (klog >> 1), Bs + chunk * 1024);
        }
        __syncthreads();
        #pragma unroll
        for (int ks = 0; ks < 2; ++ks) {
            const int ko = ks * 64 + qk * 16;
            bf16x8 a[2], b[8];
            #pragma unroll
            for (int i = 0; i < 2; ++i)
                a[i] = *(const bf16x8*)(As + (wr * 32 + i * 16 + fr) * 128 + (ko ^ sw));
            #pragma unroll
            for (int j = 0; j < 8; ++j)
                b[j] = *(const bf16x8*)(Bs + (wc * 128 + j * 16 + fr) * 128 + (ko ^ sw));
            #pragma unroll
            for (int i = 0; i < 2; ++i)
                #pragma unroll
                for (int j = 0; j < 8; ++j)
                    acc[i][j] = __builtin_amdgcn_mfma_f32_16x16x32_bf16(a[i], b[j], acc[i][j], 0, 0, 0);
        }
        __syncthreads();
    }

    // partial store: Pz[z][grow][col], each element written exactly once per z
    float* Pzs = Pz + (size_t)blockIdx.z * MR_ * A_;
    #pragma unroll
    for (int mi = 0; mi < 2; ++mi)
        #pragma unroll
        for (int ni = 0; ni < 8; ++ni) {
            const int rbase = gm0 + wr * 32 + mi * 16 + qk * 4;
            const int col   = wc * 128 + ni * 16 + fr;
            #pragma unroll
            for (int q = 0; q < 4; ++q)
                Pzs[(size_t)(rbase + q) * A_ + col] = acc[mi][ni][q];
        }
}

// attn_W (2H, 256) fp32 -> WT_BF (256, 2H) bf16, 32x32 LDS tiles
__global__ __launch_bounds__(256)
void transpose_cvt_kernel(const float* __restrict__ in, __hip_bfloat16* __restrict__ out) {
    __shared__ float tile[32][33];
    const int h0 = blockIdx.x * 32, a0 = blockIdx.y * 32;
    const int tx = threadIdx.x & 31, ty4 = threadIdx.x >> 5;
    #pragma unroll
    for (int i = 0; i < 4; ++i) {
        int r = ty4 * 4 + i;
        tile[r][tx] = in[(size_t)(h0 + r) * A_ + a0 + tx];
    }
    __syncthreads();
    #pragma unroll
    for (int i = 0; i < 4; ++i) {
        int r = ty4 * 4 + i;
        out[(size_t)(a0 + r) * H2_ + h0 + tx] = __float2bfloat16(tile[tx][r]);
    }
}

// T1[b*256+a] = attn_b[a] + sum_z Pz[z][6144+b][a]
__global__ __launch_bounds__(256)
void t1red_kernel(const float* __restrict__ Pz, const float* __restrict__ ab,
                  float* __restrict__ T1) {
    int i = blockIdx.x * 256 + threadIdx.x;       // 65536
    int b = i >> 8, a = i & 255;
    float v = ab[a];
    #pragma unroll
    for (int z = 0; z < ZSPL_; ++z)
        v += Pz[((size_t)z * MR_ + 6144 + b) * A_ + a];
    T1[i] = v;
}

// scores[q] = sum_a tanh(sum_z Pz[z][q][a] + T1[b,a]) * v[a],  q = s*256+b
__global__ __launch_bounds__(256)
void scores_kernel(const float* __restrict__ Pz, const float* __restrict__ T1,
                   const float* __restrict__ v, float* __restrict__ SC) {
    int wave = threadIdx.x >> 6, lane = threadIdx.x & 63;
    int q = blockIdx.x * 4 + wave;
    if (q >= BS_) return;
    int b = q & 255;
    float s = 0.f;
    #pragma unroll
    for (int a = lane; a < A_; a += 64) {
        float val = T1[b * A_ + a];
        #pragma unroll
        for (int z = 0; z < ZSPL_; ++z)
            val += Pz[((size_t)z * MR_ + q) * A_ + a];
        s += tanhf(val) * v[a];
    }
    #pragma unroll
    for (int off = 32; off; off >>= 1) s += __shfl_down(s, off, 64);
    if (lane == 0) SC[q] = s;
}

// weighted[b,h] = softmax_s(SC[:,b]) . enc_f32[:,b,h]
__global__ __launch_bounds__(256)
void weighted_f32_kernel(const float4* __restrict__ E4, const float* __restrict__ SC,
                         float4* __restrict__ WT4) {
    int g = blockIdx.x * 256 + threadIdx.x;            // B_*H_/4
    int b = g / (H_ / 4), c = g % (H_ / 4);
    float sc[S_];
    float mx = -1e30f;
    #pragma unroll
    for (int s = 0; s < S_; ++s) { sc[s] = SC[s * B_ + b]; mx = fmaxf(mx, sc[s]); }
    float sum = 0.f;
    #pragma unroll
    for (int s = 0; s < S_; ++s) { sc[s] = expf(sc[s] - mx); sum += sc[s]; }
    float inv = 1.f / sum;
    float4 acc = make_float4(0.f, 0.f, 0.f, 0.f);
    #pragma unroll
    for (int s = 0; s < S_; ++s) {
        float w = sc[s] * inv;
        float4 ev = E4[(size_t)(s * B_ + b) * (H_ / 4) + c];
        acc.x += w * ev.x; acc.y += w * ev.y;
        acc.z += w * ev.z; acc.w += w * ev.w;
    }
    WT4[(size_t)b * (H_ / 4) + c] = acc;
}

// CAT_T builder (y<4) + phase-B weight prep (y==4, grid-stride).
__global__ __launch_bounds__(256)
void catT_prepB_kernel(const float* __restrict__ inp, const float* __restrict__ WT,
                       const float* __restrict__ hid, __hip_bfloat16* __restrict__ CT,
                       const float* __restrict__ adj, const float* __restrict__ Wru,
                       const float* __restrict__ Wc, __hip_bfloat16* __restrict__ ADJ,
                       __hip_bfloat16* __restrict__ WRUT, __hip_bfloat16* __restrict__ WCT) {
    const int tid = threadIdx.x;
    if (blockIdx.y == 4) {
        for (int i = blockIdx.x * 256 + tid; i < 102400; i += 65536) {
            if (i < 65536) {
                int r = i >> 8, c = i & 255;
                ADJ[i] = __float2bfloat16((r < N_ && c < N_) ? adj[r * N_ + c] : 0.f);
            } else if (i < 90112) {
                int idx = i - 65536;
                int j = idx / FP_, f = idx % FP_;
                WRUT[idx] = __float2bfloat16(f < NF_ ? Wru[f * 128 + j] : 0.f);
            } else {
                int idx = i - 90112;
                int j = idx / FP_, f = idx % FP_;
                WCT[idx] = __float2bfloat16(f < NF_ ? Wc[f * 64 + j] : 0.f);
            }
        }
        return;
    }
    __shared__ float ww[64][65];
    __shared__ float wh[64][65];
    __shared__ float wi[64];
    const int b = blockIdx.x;
    const int k0 = blockIdx.y * 64;
    #pragma unroll
    for (int i = 0; i < 16; ++i) {
        int idx = tid + i * 256;
        int kn = idx >> 6, f = idx & 63;
        int k = k0 + kn;
        bool vld = (k < N_);
        ww[kn][f] = vld ? WT [(size_t)b * H_ + k * 64 + f] : 0.f;
        wh[kn][f] = vld ? hid[(size_t)b * H_ + k * 64 + f] : 0.f;
    }
    if (tid < 64) wi[tid] = (k0 + tid < N_) ? inp[b * N_ + k0 + tid] : 0.f;
    __syncthreads();
    #pragma unroll
    for (int i = 0; i < 6; ++i) {
        int cid = tid + i * 256;
        int f = cid >> 3, kk = (cid & 7) * 8;
        union { __hip_bfloat16 h[8]; bf16x8 v; } pk;
        #pragma unroll
        for (int j = 0; j < 8; ++j) {
            float x;
            if (f == 0)        x = wi[kk + j];
            else if (f <= 64)  x = ww[kk + j][f - 1];
            else if (f <= 128) x = wh[kk + j][f - 65];
            else               x = 0.f;
            pk.h[j] = __float2bfloat16(x);
        }
        *(bf16x8*)(CT + ((size_t)b * FP_ + f) * KP_ + k0 + kk) = pk.v;
    }
}

// RH_T builder: rows (b*64+u), cols k: r[k,b,u]*h[b,k,u], bf16
__global__ __launch_bounds__(256)
void rhT_kernel(const float* __restrict__ RU, const float* __restrict__ hid,
                __hip_bfloat16* __restrict__ RT) {
    __shared__ float rh[64][65];
    const int b = blockIdx.x, k0 = blockIdx.y * 64, tid = threadIdx.x;
    #pragma unroll
    for (int i = 0; i < 16; ++i) {
        int idx = tid + i * 256;
        int kn = idx >> 6, u = idx & 63;
        int k = k0 + kn;
        float v = 0.f;
        if (k < N_)
            v = RU[((size_t)k * 256 + b) * 128 + u] * hid[(size_t)b * H_ + k * 64 + u];
        rh[kn][u] = v;
    }
    __syncthreads();
    #pragma unroll
    for (int i = 0; i < 2; ++i) {
        int cid = tid + i * 256;
        int u = cid >> 3, kk = (cid & 7) * 8;
        union { __hip_bfloat16 h[8]; bf16x8 v; } pk;
        #pragma unroll
        for (int j = 0; j < 8; ++j) pk.h[j] = __float2bfloat16(rh[kk + j][u]);
        *(bf16x8*)(RT + ((size_t)b * 64 + u) * KP_ + k0 + kk) = pk.v;
    }
}

extern "C" void kernel_launch(void* const* d_in, const int* in_sizes, int n_in,
                              void* d_out, int out_size, void* d_ws, size_t ws_size,
                              hipStream_t stream) {
    const float* inp    = (const float*)d_in[0];
    const float* enc    = (const float*)d_in[1];
    const float* hid    = (const float*)d_in[2];
    const float* adj    = (const float*)d_in[3];
    const float* attn_W = (const float*)d_in[4];
    const float* attn_b = (const float*)d_in[5];
    const float* attn_v = (const float*)d_in[6];
    const float* W_ru   = (const float*)d_in[7];
    const float* b_ru   = (const float*)d_in[8];
    const float* W_c    = (const float*)d_in[9];
    const float* b_c    = (const float*)d_in[10];
    const float* proj_W = (const float*)d_in[11];
    const float* proj_b = (const float*)d_in[12];

    float* out0 = (float*)d_out;
    float* out2 = out0 + (size_t)B_ * N_;

    // Workspace (float offsets) — R8-validated region map kept.
    // Pz (z=9 partials, 14,745,600 fl) lives in the attention-phase span of
    // BIG ([0, 40697856)); CAT_T overwrites it only after scores consumed it.
    float* ws  = (float*)d_ws;
    float* T1  = ws;                      // 65536
    float* Pold= T1 + 65536;              // 1572864 (unused; layout stable)
    float* SC  = Pold + 1572864;          // 6144
    float* AW  = SC + 6144;               // 6144 (unused; layout stable)
    float* WT  = AW + 6144;               // 3391488
    float* BIG = WT + 3391488;            // off 5042176
    float* Pz  = BIG;                     // [0, 14745600)
    __hip_bfloat16* WT_BF  = (__hip_bfloat16*)(BIG + 40697856);
    __hip_bfloat16* CAT_T  = (__hip_bfloat16*)BIG;
    __hip_bfloat16* MB_BF  = (__hip_bfloat16*)(BIG + 6291456);
    __hip_bfloat16* RH_T   = (__hip_bfloat16*)(BIG + 12582912);
    float*          RU     = BIG + 14680064;
    __hip_bfloat16* ADJ_BF = (__hip_bfloat16*)(BIG + 21463040);
    __hip_bfloat16* WRUT   = (__hip_bfloat16*)(BIG + 21495808);
    __hip_bfloat16* WCT    = (__hip_bfloat16*)(BIG + 21508096);

    // --- prep: attn_W transpose (no init needed — Pz/T1 fully overwritten) ---
    transpose_cvt_kernel<<<dim3(H2_/32, A_/32), 256, 0, stream>>>(attn_W, WT_BF);

    // --- attention GEMM: partial stores, NO global atomics ---
    gemm_enchid<<<dim3(1, 100, ZSPL_), 256, 0, stream>>>(
        enc, hid, WT_BF, Pz, 1472, 23);

    // T1 = attn_b + sum_z hid-partials
    t1red_kernel<<<256, 256, 0, stream>>>(Pz, attn_b, T1);
    // scores: z-sum of enc-partials + T1, tanh, dot v
    scores_kernel<<<BS_/4, 256, 0, stream>>>(Pz, T1, attn_v, SC);
    weighted_f32_kernel<<<(B_*(H_/4))/256, 256, 0, stream>>>(
        (const float4*)enc, SC, (float4*)WT);

    // --- phase B (Pz dead; CAT_T overlays it) ---
    catT_prepB_kernel<<<dim3(256, 5), 256, 0, stream>>>(
        inp, WT, hid, CAT_T, adj, W_ru, W_c, ADJ_BF, WRUT, WCT);

    mfma_gemm<64,64,2><<<dim3(768,4,1), 256, 0, stream>>>(
        ADJ_BF, KP_, CAT_T, KP_, MB_BF, 49152, 0, 4,
        nullptr, nullptr, nullptr, nullptr, nullptr, nullptr, nullptr, nullptr);

    mfma_gemm<64,64,4><<<dim3(2,828,1), 256, 0, stream>>>(
        MB_BF, FP_, WRUT, FP_, RU, 128, 0, 3,
        b_ru, nullptr, nullptr, nullptr, nullptr, nullptr, nullptr, nullptr);

    rhT_kernel<<<dim3(256,4), 256, 0, stream>>>(RU, hid, RH_T);

    mfma_gemm<64,64,3><<<dim3(256,4,1), 256, 0, stream>>>(
        ADJ_BF, KP_, RH_T, KP_, MB_BF, 0, 0, 4,
        nullptr, nullptr, nullptr, nullptr, nullptr, nullptr, nullptr, nullptr);

    // c-GEMM + GRU + FUSED projection -> out2 (newh) and out0
    mfma_gemm<64,64,5><<<dim3(1,828,1), 256, 0, stream>>>(
        MB_BF, FP_, WCT, FP_, out2, 0, 0, 3,
        b_c, RU, hid, WT, proj_W, proj_b, inp, out0);
}

// Round 16
// 265.524 us; speedup vs baseline: 1.2894x; 1.0650x over previous
//
#include <hip/hip_runtime.h>
#include <hip/hip_bf16.h>
#include <math.h>

// Problem constants
#define B_ 256
#define S_ 24
#define N_ 207
#define U_ 64
#define A_ 256
#define H_ (N_*U_)          // 13248
#define H2_ (2*H_)          // 26496
#define BS_ (B_*S_)         // 6144
#define NF_ 129             // 1 + 2U
#define FP_ 192             // padded feature width of MB rows
#define KP_ 256             // padded node count (K of adj GEMMs)
#define MR_ 6400            // unified attention rows: 6144 enc + 256 hid
#define ZSPL_ 9             // split-K partials

typedef __attribute__((ext_vector_type(8))) short bf16x8;
typedef __attribute__((ext_vector_type(4))) float f32x4;

#define GAS __attribute__((address_space(1)))
#define LAS __attribute__((address_space(3)))

static __device__ __forceinline__ void gload16(const __hip_bfloat16* g, void* lds) {
    __builtin_amdgcn_global_load_lds((const GAS uint32_t*)g, (LAS uint32_t*)lds, 16, 0, 0);
}

// ---------------------------------------------------------------------------
// bf16 MFMA GEMM template (R8-R15-validated core). C = A[M,K] @ BT[N,K]^T.
// EPI: 2 = bf16 store; 3 = bf16 remap (rh cols); 4 = sigmoid store;
//      5 = GRU epilogue + FUSED output projection (BN=64 required).
// ---------------------------------------------------------------------------
template<int BM, int BN, int EPI>
__global__ __launch_bounds__(256)
void mfma_gemm(const __hip_bfloat16* __restrict__ A, int lda,
               const __hip_bfloat16* __restrict__ BT, int ldb,
               void* __restrict__ Cv, int ldc,
               int kchunk, int niter,
               const float* __restrict__ ep0,
               const float* __restrict__ ep1,
               const float* __restrict__ ep2,
               const float* __restrict__ e_wt,
               const float* __restrict__ e_pw,
               const float* __restrict__ e_pb,
               const float* __restrict__ e_in,
               float* __restrict__ e_o0)
{
    constexpr int FM = BM / 32, FN = BN / 32;
    __shared__ __align__(128) char smem[(BM + BN) * 128];
    char* As = smem;
    char* Bs = smem + BM * 128;

    const int tid  = threadIdx.x;
    const int lane = tid & 63;
    const int wid  = tid >> 6;
    const int wr   = wid >> 1, wc = wid & 1;

    const int n0 = blockIdx.x * BN;
    const int m0 = blockIdx.y * BM;
    const long k0 = (long)blockIdx.z * kchunk;

    const int qk = lane >> 4;
    const int fr = lane & 15;
    const int sw = (lane & 7) << 4;

    f32x4 acc[FM][FN] = {};

    for (int it = 0; it < niter; ++it) {
        const long kb = k0 + (long)it * 64;
        #pragma unroll
        for (int p = 0; p < BM / 32; ++p) {
            const int chunk = p * 4 + wid;
            const int blk   = chunk * 64 + lane;
            const int r     = blk >> 3;
            const int klog  = ((blk & 7) << 4) ^ ((r & 7) << 4);
            gload16(A + (size_t)(m0 + r) * lda + kb + (klog >> 1), As + chunk * 1024);
        }
        #pragma unroll
        for (int p = 0; p < BN / 32; ++p) {
            const int chunk = p * 4 + wid;
            const int blk   = chunk * 64 + lane;
            const int r     = blk >> 3;
            const int klog  = ((blk & 7) << 4) ^ ((r & 7) << 4);
            gload16(BT + (size_t)(n0 + r) * ldb + kb + (klog >> 1), Bs + chunk * 1024);
        }
        __syncthreads();
        #pragma unroll
        for (int ks = 0; ks < 2; ++ks) {
            const int ko = ks * 64 + qk * 16;
            bf16x8 a[FM], b[FN];
            #pragma unroll
            for (int i = 0; i < FM; ++i)
                a[i] = *(const bf16x8*)(As + (wr * (BM/2) + i * 16 + fr) * 128 + (ko ^ sw));
            #pragma unroll
            for (int j = 0; j < FN; ++j)
                b[j] = *(const bf16x8*)(Bs + (wc * (BN/2) + j * 16 + fr) * 128 + (ko ^ sw));
            #pragma unroll
            for (int i = 0; i < FM; ++i)
                #pragma unroll
                for (int j = 0; j < FN; ++j)
                    acc[i][j] = __builtin_amdgcn_mfma_f32_16x16x32_bf16(a[i], b[j], acc[i][j], 0, 0, 0);
        }
        __syncthreads();
    }

    // EPI=5 projection reduction buffer (aliases LDS, dead after last sync)
    float* rsum = (float*)smem;
    if (EPI == 5) {
        if (tid < BM) rsum[tid] = 0.f;
        __syncthreads();
    }
    float tpart[FM][4];
    if (EPI == 5) {
        #pragma unroll
        for (int mi = 0; mi < FM; ++mi)
            #pragma unroll
            for (int q = 0; q < 4; ++q) tpart[mi][q] = 0.f;
    }

    // C/D layout: col=lane&15, row=(lane>>4)*4+reg  [m89-verified]
    #pragma unroll
    for (int mi = 0; mi < FM; ++mi)
        #pragma unroll
        for (int ni = 0; ni < FN; ++ni) {
            const int rbase = m0 + wr * (BM/2) + mi * 16 + qk * 4;
            const int col   = n0 + wc * (BN/2) + ni * 16 + fr;
            #pragma unroll
            for (int q = 0; q < 4; ++q) {
                const int row = rbase + q;
                const float v = acc[mi][ni][q];
                if (EPI == 2) {
                    ((__hip_bfloat16*)Cv)[(size_t)row * ldc + col] = __float2bfloat16(v);
                } else if (EPI == 3) {
                    const int bb = col >> 6, uu = col & 63;
                    ((__hip_bfloat16*)Cv)[((size_t)row * 256 + bb) * FP_ + 65 + uu] = __float2bfloat16(v);
                } else if (EPI == 4) {
                    float sv = v + ep0[col];
                    ((float*)Cv)[(size_t)row * ldc + col] = 1.f / (1.f + expf(-sv));
                } else { // EPI == 5
                    const int nn = row >> 8, bb = row & 255;
                    float cg = tanhf(v + ep0[col]);
                    float ug = ep1[(size_t)row * 128 + 64 + col];
                    const size_t hoff = (size_t)bb * H_ + nn * U_ + col;
                    float nh = ug * ep2[hoff] + (1.f - ug) * cg;
                    ((float*)Cv)[hoff] = nh;
                    tpart[mi][q] += nh * e_pw[col] + e_wt[hoff] * e_pw[64 + col];
                }
            }
        }

    if (EPI == 5) {
        #pragma unroll
        for (int mi = 0; mi < FM; ++mi)
            #pragma unroll
            for (int q = 0; q < 4; ++q) {
                float t = tpart[mi][q];
                #pragma unroll
                for (int off = 8; off; off >>= 1) t += __shfl_xor(t, off, 16);
                if (fr == 0) {
                    const int rloc = wr * (BM/2) + mi * 16 + qk * 4 + q;
                    atomicAdd(&rsum[rloc], t);   // LDS atomic — cheap
                }
            }
        __syncthreads();
        if (tid < BM) {
            const int row = m0 + tid;
            const int nn = row >> 8, bb = row & 255;
            e_o0[bb * N_ + nn] = rsum[tid] + e_in[bb * N_ + nn] * e_pw[128] + e_pb[0];
        }
    }
}

// ---------------------------------------------------------------------------
// Fused attention GEMM, BM=64/BN=256, split-K z=9, partial stores (no global
// atomics — R15 win), now DOUBLE-BUFFERED 2-phase pipeline (T3-minimum):
// per iter: issue next B gload_lds + next A global_loads BEFORE current MFMA
// (loads fly under compute); cvt+ds_write A to alt buffer; ONE barrier/iter.
// (R15 residual: ~145us at 1 TB/s / 8% MfmaUtil = per-iter vmcnt+barrier
// serialization — each iter paid full HBM latency with no overlap.)
// ---------------------------------------------------------------------------
__global__ __launch_bounds__(256)
void gemm_enchid(const float* __restrict__ Aenc,
                 const float* __restrict__ Ahid,
                 const __hip_bfloat16* __restrict__ WTBF,
                 float* __restrict__ Pz,
                 int kchunk, int niter)
{
    __shared__ __align__(128) char smem[2 * (64 + 256) * 128];   // 80 KB
    // buffer layout: buf k at smem + k*40960; As = buf, Bs = buf + 8192

    const int tid  = threadIdx.x;
    const int lane = tid & 63;
    const int wid  = tid >> 6;
    const int wr   = wid >> 1, wc = wid & 1;

    const bool isH = (blockIdx.y >= 96);
    const float* A = isH ? Ahid : Aenc;
    const int lm0  = (isH ? (blockIdx.y - 96) : blockIdx.y) * 64;  // local rows
    const int gm0  = (isH ? 6144 : 0) + lm0;                       // unified rows
    const __hip_bfloat16* BT = WTBF + (isH ? 0 : H_);

    const long k0 = (long)blockIdx.z * kchunk;

    const int qk = lane >> 4;
    const int fr = lane & 15;
    const int sw = (lane & 7) << 4;

    // Per-thread A-chunk geometry (2 chunks/thread, constant across iters)
    int arow[2], akc[2];
    #pragma unroll
    for (int h = 0; h < 2; ++h) {
        const int c = h * 256 + tid;
        arow[h] = c >> 3;
        akc[h]  = c & 7;
    }

    f32x4 acc[2][8] = {};
    float4 pfx[2], pfy[2];          // A prefetch registers

    // ---- prologue: stage tile 0 into buf0 ----
    {
        const long kb = k0;
        #pragma unroll
        for (int p = 0; p < 8; ++p) {
            const int chunk = p * 4 + wid;
            const int blk   = chunk * 64 + lane;
            const int r     = blk >> 3;
            const int klog  = ((blk & 7) << 4) ^ ((r & 7) << 4);
            gload16(BT + (size_t)r * H2_ + kb + (klog >> 1), smem + 8192 + chunk * 1024);
        }
        #pragma unroll
        for (int h = 0; h < 2; ++h) {
            const float* src = A + (size_t)(lm0 + arow[h]) * H_ + kb + akc[h] * 8;
            pfx[h] = *(const float4*)(src);
            pfy[h] = *(const float4*)(src + 4);
        }
        #pragma unroll
        for (int h = 0; h < 2; ++h) {
            union { __hip_bfloat16 hh[8]; int4 u; } pk;
            pk.hh[0] = __float2bfloat16(pfx[h].x); pk.hh[1] = __float2bfloat16(pfx[h].y);
            pk.hh[2] = __float2bfloat16(pfx[h].z); pk.hh[3] = __float2bfloat16(pfx[h].w);
            pk.hh[4] = __float2bfloat16(pfy[h].x); pk.hh[5] = __float2bfloat16(pfy[h].y);
            pk.hh[6] = __float2bfloat16(pfy[h].z); pk.hh[7] = __float2bfloat16(pfy[h].w);
            *(int4*)(smem + arow[h] * 128 + ((akc[h] << 4) ^ ((arow[h] & 7) << 4))) = pk.u;
        }
        __syncthreads();   // drains gloads (vmcnt) + ds_writes (lgkmcnt)
    }

    int cur = 0;
    for (int it = 0; it < niter; ++it) {
        char* curbuf = smem + cur * 40960;
        char* altbuf = smem + (cur ^ 1) * 40960;
        const bool pf = (it + 1 < niter);
        const long kbn = k0 + (long)(it + 1) * 64;

        // ---- issue next tile's loads (fly under this tile's MFMA) ----
        if (pf) {
            #pragma unroll
            for (int p = 0; p < 8; ++p) {
                const int chunk = p * 4 + wid;
                const int blk   = chunk * 64 + lane;
                const int r     = blk >> 3;
                const int klog  = ((blk & 7) << 4) ^ ((r & 7) << 4);
                gload16(BT + (size_t)r * H2_ + kbn + (klog >> 1), altbuf + 8192 + chunk * 1024);
            }
            #pragma unroll
            for (int h = 0; h < 2; ++h) {
                const float* src = A + (size_t)(lm0 + arow[h]) * H_ + kbn + akc[h] * 8;
                pfx[h] = *(const float4*)(src);
                pfy[h] = *(const float4*)(src + 4);
            }
        }

        // ---- compute current tile ----
        #pragma unroll
        for (int ks = 0; ks < 2; ++ks) {
            const int ko = ks * 64 + qk * 16;
            bf16x8 a[2], b[8];
            #pragma unroll
            for (int i = 0; i < 2; ++i)
                a[i] = *(const bf16x8*)(curbuf + (wr * 32 + i * 16 + fr) * 128 + (ko ^ sw));
            #pragma unroll
            for (int j = 0; j < 8; ++j)
                b[j] = *(const bf16x8*)(curbuf + 8192 + (wc * 128 + j * 16 + fr) * 128 + (ko ^ sw));
            #pragma unroll
            for (int i = 0; i < 2; ++i)
                #pragma unroll
                for (int j = 0; j < 8; ++j)
                    acc[i][j] = __builtin_amdgcn_mfma_f32_16x16x32_bf16(a[i], b[j], acc[i][j], 0, 0, 0);
        }

        // ---- convert + write next A into alt buffer ----
        if (pf) {
            #pragma unroll
            for (int h = 0; h < 2; ++h) {
                union { __hip_bfloat16 hh[8]; int4 u; } pk;
                pk.hh[0] = __float2bfloat16(pfx[h].x); pk.hh[1] = __float2bfloat16(pfx[h].y);
                pk.hh[2] = __float2bfloat16(pfx[h].z); pk.hh[3] = __float2bfloat16(pfx[h].w);
                pk.hh[4] = __float2bfloat16(pfy[h].x); pk.hh[5] = __float2bfloat16(pfy[h].y);
                pk.hh[6] = __float2bfloat16(pfy[h].z); pk.hh[7] = __float2bfloat16(pfy[h].w);
                *(int4*)(altbuf + arow[h] * 128 + ((akc[h] << 4) ^ ((arow[h] & 7) << 4))) = pk.u;
            }
        }
        __syncthreads();   // alt fully staged; cur reads done
        cur ^= 1;
    }

    // partial store: Pz[z][grow][col], each element written exactly once per z
    float* Pzs = Pz + (size_t)blockIdx.z * MR_ * A_;
    #pragma unroll
    for (int mi = 0; mi < 2; ++mi)
        #pragma unroll
        for (int ni = 0; ni < 8; ++ni) {
            const int rbase = gm0 + wr * 32 + mi * 16 + qk * 4;
            const int col   = wc * 128 + ni * 16 + fr;
            #pragma unroll
            for (int q = 0; q < 4; ++q)
                Pzs[(size_t)(rbase + q) * A_ + col] = acc[mi][ni][q];
        }
}

// attn_W (2H, 256) fp32 -> WT_BF (256, 2H) bf16, 32x32 LDS tiles
__global__ __launch_bounds__(256)
void transpose_cvt_kernel(const float* __restrict__ in, __hip_bfloat16* __restrict__ out) {
    __shared__ float tile[32][33];
    const int h0 = blockIdx.x * 32, a0 = blockIdx.y * 32;
    const int tx = threadIdx.x & 31, ty4 = threadIdx.x >> 5;
    #pragma unroll
    for (int i = 0; i < 4; ++i) {
        int r = ty4 * 4 + i;
        tile[r][tx] = in[(size_t)(h0 + r) * A_ + a0 + tx];
    }
    __syncthreads();
    #pragma unroll
    for (int i = 0; i < 4; ++i) {
        int r = ty4 * 4 + i;
        out[(size_t)(a0 + r) * H2_ + h0 + tx] = __float2bfloat16(tile[tx][r]);
    }
}

// T1[b*256+a] = attn_b[a] + sum_z Pz[z][6144+b][a]
__global__ __launch_bounds__(256)
void t1red_kernel(const float* __restrict__ Pz, const float* __restrict__ ab,
                  float* __restrict__ T1) {
    int i = blockIdx.x * 256 + threadIdx.x;       // 65536
    int b = i >> 8, a = i & 255;
    float v = ab[a];
    #pragma unroll
    for (int z = 0; z < ZSPL_; ++z)
        v += Pz[((size_t)z * MR_ + 6144 + b) * A_ + a];
    T1[i] = v;
}

// scores[q] = sum_a tanh(sum_z Pz[z][q][a] + T1[b,a]) * v[a],  q = s*256+b
__global__ __launch_bounds__(256)
void scores_kernel(const float* __restrict__ Pz, const float* __restrict__ T1,
                   const float* __restrict__ v, float* __restrict__ SC) {
    int wave = threadIdx.x >> 6, lane = threadIdx.x & 63;
    int q = blockIdx.x * 4 + wave;
    if (q >= BS_) return;
    int b = q & 255;
    float s = 0.f;
    #pragma unroll
    for (int a = lane; a < A_; a += 64) {
        float val = T1[b * A_ + a];
        #pragma unroll
        for (int z = 0; z < ZSPL_; ++z)
            val += Pz[((size_t)z * MR_ + q) * A_ + a];
        s += tanhf(val) * v[a];
    }
    #pragma unroll
    for (int off = 32; off; off >>= 1) s += __shfl_down(s, off, 64);
    if (lane == 0) SC[q] = s;
}

// weighted[b,h] = softmax_s(SC[:,b]) . enc_f32[:,b,h]
__global__ __launch_bounds__(256)
void weighted_f32_kernel(const float4* __restrict__ E4, const float* __restrict__ SC,
                         float4* __restrict__ WT4) {
    int g = blockIdx.x * 256 + threadIdx.x;            // B_*H_/4
    int b = g / (H_ / 4), c = g % (H_ / 4);
    float sc[S_];
    float mx = -1e30f;
    #pragma unroll
    for (int s = 0; s < S_; ++s) { sc[s] = SC[s * B_ + b]; mx = fmaxf(mx, sc[s]); }
    float sum = 0.f;
    #pragma unroll
    for (int s = 0; s < S_; ++s) { sc[s] = expf(sc[s] - mx); sum += sc[s]; }
    float inv = 1.f / sum;
    float4 acc = make_float4(0.f, 0.f, 0.f, 0.f);
    #pragma unroll
    for (int s = 0; s < S_; ++s) {
        float w = sc[s] * inv;
        float4 ev = E4[(size_t)(s * B_ + b) * (H_ / 4) + c];
        acc.x += w * ev.x; acc.y += w * ev.y;
        acc.z += w * ev.z; acc.w += w * ev.w;
    }
    WT4[(size_t)b * (H_ / 4) + c] = acc;
}

// CAT_T builder (y<4) + phase-B weight prep (y==4, grid-stride).
__global__ __launch_bounds__(256)
void catT_prepB_kernel(const float* __restrict__ inp, const float* __restrict__ WT,
                       const float* __restrict__ hid, __hip_bfloat16* __restrict__ CT,
                       const float* __restrict__ adj, const float* __restrict__ Wru,
                       const float* __restrict__ Wc, __hip_bfloat16* __restrict__ ADJ,
                       __hip_bfloat16* __restrict__ WRUT, __hip_bfloat16* __restrict__ WCT) {
    const int tid = threadIdx.x;
    if (blockIdx.y == 4) {
        for (int i = blockIdx.x * 256 + tid; i < 102400; i += 65536) {
            if (i < 65536) {
                int r = i >> 8, c = i & 255;
                ADJ[i] = __float2bfloat16((r < N_ && c < N_) ? adj[r * N_ + c] : 0.f);
            } else if (i < 90112) {
                int idx = i - 65536;
                int j = idx / FP_, f = idx % FP_;
                WRUT[idx] = __float2bfloat16(f < NF_ ? Wru[f * 128 + j] : 0.f);
            } else {
                int idx = i - 90112;
                int j = idx / FP_, f = idx % FP_;
                WCT[idx] = __float2bfloat16(f < NF_ ? Wc[f * 64 + j] : 0.f);
            }
        }
        return;
    }
    __shared__ float ww[64][65];
    __shared__ float wh[64][65];
    __shared__ float wi[64];
    const int b = blockIdx.x;
    const int k0 = blockIdx.y * 64;
    #pragma unroll
    for (int i = 0; i < 16; ++i) {
        int idx = tid + i * 256;
        int kn = idx >> 6, f = idx & 63;
        int k = k0 + kn;
        bool vld = (k < N_);
        ww[kn][f] = vld ? WT [(size_t)b * H_ + k * 64 + f] : 0.f;
        wh[kn][f] = vld ? hid[(size_t)b * H_ + k * 64 + f] : 0.f;
    }
    if (tid < 64) wi[tid] = (k0 + tid < N_) ? inp[b * N_ + k0 + tid] : 0.f;
    __syncthreads();
    #pragma unroll
    for (int i = 0; i < 6; ++i) {
        int cid = tid + i * 256;
        int f = cid >> 3, kk = (cid & 7) * 8;
        union { __hip_bfloat16 h[8]; bf16x8 v; } pk;
        #pragma unroll
        for (int j = 0; j < 8; ++j) {
            float x;
            if (f == 0)        x = wi[kk + j];
            else if (f <= 64)  x = ww[kk + j][f - 1];
            else if (f <= 128) x = wh[kk + j][f - 65];
            else               x = 0.f;
            pk.h[j] = __float2bfloat16(x);
        }
        *(bf16x8*)(CT + ((size_t)b * FP_ + f) * KP_ + k0 + kk) = pk.v;
    }
}

// RH_T builder: rows (b*64+u), cols k: r[k,b,u]*h[b,k,u], bf16
__global__ __launch_bounds__(256)
void rhT_kernel(const float* __restrict__ RU, const float* __restrict__ hid,
                __hip_bfloat16* __restrict__ RT) {
    __shared__ float rh[64][65];
    const int b = blockIdx.x, k0 = blockIdx.y * 64, tid = threadIdx.x;
    #pragma unroll
    for (int i = 0; i < 16; ++i) {
        int idx = tid + i * 256;
        int kn = idx >> 6, u = idx & 63;
        int k = k0 + kn;
        float v = 0.f;
        if (k < N_)
            v = RU[((size_t)k * 256 + b) * 128 + u] * hid[(size_t)b * H_ + k * 64 + u];
        rh[kn][u] = v;
    }
    __syncthreads();
    #pragma unroll
    for (int i = 0; i < 2; ++i) {
        int cid = tid + i * 256;
        int u = cid >> 3, kk = (cid & 7) * 8;
        union { __hip_bfloat16 h[8]; bf16x8 v; } pk;
        #pragma unroll
        for (int j = 0; j < 8; ++j) pk.h[j] = __float2bfloat16(rh[kk + j][u]);
        *(bf16x8*)(RT + ((size_t)b * 64 + u) * KP_ + k0 + kk) = pk.v;
    }
}

extern "C" void kernel_launch(void* const* d_in, const int* in_sizes, int n_in,
                              void* d_out, int out_size, void* d_ws, size_t ws_size,
                              hipStream_t stream) {
    const float* inp    = (const float*)d_in[0];
    const float* enc    = (const float*)d_in[1];
    const float* hid    = (const float*)d_in[2];
    const float* adj    = (const float*)d_in[3];
    const float* attn_W = (const float*)d_in[4];
    const float* attn_b = (const float*)d_in[5];
    const float* attn_v = (const float*)d_in[6];
    const float* W_ru   = (const float*)d_in[7];
    const float* b_ru   = (const float*)d_in[8];
    const float* W_c    = (const float*)d_in[9];
    const float* b_c    = (const float*)d_in[10];
    const float* proj_W = (const float*)d_in[11];
    const float* proj_b = (const float*)d_in[12];

    float* out0 = (float*)d_out;
    float* out2 = out0 + (size_t)B_ * N_;

    // Workspace (float offsets) — R8-validated region map kept.
    float* ws  = (float*)d_ws;
    float* T1  = ws;                      // 65536
    float* Pold= T1 + 65536;              // 1572864 (unused; layout stable)
    float* SC  = Pold + 1572864;          // 6144
    float* AW  = SC + 6144;               // 6144 (unused; layout stable)
    float* WT  = AW + 6144;               // 3391488
    float* BIG = WT + 3391488;            // off 5042176
    float* Pz  = BIG;                     // [0, 14745600)
    __hip_bfloat16* WT_BF  = (__hip_bfloat16*)(BIG + 40697856);
    __hip_bfloat16* CAT_T  = (__hip_bfloat16*)BIG;
    __hip_bfloat16* MB_BF  = (__hip_bfloat16*)(BIG + 6291456);
    __hip_bfloat16* RH_T   = (__hip_bfloat16*)(BIG + 12582912);
    float*          RU     = BIG + 14680064;
    __hip_bfloat16* ADJ_BF = (__hip_bfloat16*)(BIG + 21463040);
    __hip_bfloat16* WRUT   = (__hip_bfloat16*)(BIG + 21495808);
    __hip_bfloat16* WCT    = (__hip_bfloat16*)(BIG + 21508096);

    // --- prep: attn_W transpose ---
    transpose_cvt_kernel<<<dim3(H2_/32, A_/32), 256, 0, stream>>>(attn_W, WT_BF);

    // --- attention GEMM: double-buffered 2-phase, partial stores ---
    gemm_enchid<<<dim3(1, 100, ZSPL_), 256, 0, stream>>>(
        enc, hid, WT_BF, Pz, 1472, 23);

    t1red_kernel<<<256, 256, 0, stream>>>(Pz, attn_b, T1);
    scores_kernel<<<BS_/4, 256, 0, stream>>>(Pz, T1, attn_v, SC);
    weighted_f32_kernel<<<(B_*(H_/4))/256, 256, 0, stream>>>(
        (const float4*)enc, SC, (float4*)WT);

    // --- phase B (Pz dead; CAT_T overlays it) ---
    catT_prepB_kernel<<<dim3(256, 5), 256, 0, stream>>>(
        inp, WT, hid, CAT_T, adj, W_ru, W_c, ADJ_BF, WRUT, WCT);

    mfma_gemm<64,64,2><<<dim3(768,4,1), 256, 0, stream>>>(
        ADJ_BF, KP_, CAT_T, KP_, MB_BF, 49152, 0, 4,
        nullptr, nullptr, nullptr, nullptr, nullptr, nullptr, nullptr, nullptr);

    mfma_gemm<64,64,4><<<dim3(2,828,1), 256, 0, stream>>>(
        MB_BF, FP_, WRUT, FP_, RU, 128, 0, 3,
        b_ru, nullptr, nullptr, nullptr, nullptr, nullptr, nullptr, nullptr);

    rhT_kernel<<<dim3(256,4), 256, 0, stream>>>(RU, hid, RH_T);

    mfma_gemm<64,64,3><<<dim3(256,4,1), 256, 0, stream>>>(
        ADJ_BF, KP_, RH_T, KP_, MB_BF, 0, 0, 4,
        nullptr, nullptr, nullptr, nullptr, nullptr, nullptr, nullptr, nullptr);

    // c-GEMM + GRU + FUSED projection -> out2 (newh) and out0
    mfma_gemm<64,64,5><<<dim3(1,828,1), 256, 0, stream>>>(
        MB_BF, FP_, WCT, FP_, out2, 0, 0, 3,
        b_c, RU, hid, WT, proj_W, proj_b, inp, out0);
}